// Round 16
// baseline (52.345 us; speedup 1.0000x reference)
//
#include <hip/hip_runtime.h>
#include <hip/hip_bf16.h>

#define N_NODES 50000
#define N_EDGES 640000

typedef __attribute__((ext_vector_type(8))) _Float16 f16x8;
typedef __attribute__((ext_vector_type(4))) float f32x4;

static __device__ __forceinline__ float sgpr_f(const float* p) {
    return __uint_as_float(__builtin_amdgcn_readfirstlane(__float_as_uint(*p)));
}

// ---- tiny pre-pass: W2/b2 f32 -> f16 table in d_ws (17 tiles x 512) ----
// layout: w2h[(c*16 + o)*32 + k], c=16 is the b2 bias tile.
__global__ __launch_bounds__(256)
void w2_convert_kernel(const float* __restrict__ W2,
                       const float* __restrict__ b2,
                       _Float16* __restrict__ w2h)
{
    const int i = blockIdx.x * 256 + threadIdx.x;   // 0 .. 17*512-1
    if (i >= 17 * 512) return;
    const int c   = i >> 9;
    const int rem = i & 511;
    w2h[i] = (_Float16)(c < 16 ? W2[c * 512 + rem] : b2[rem]);
}

__global__ __launch_bounds__(256)
void edge_hyper_kernel(const float* __restrict__ x,
                       const int* __restrict__ ei,      // int32 [2][E]
                       const float* __restrict__ ev,
                       const float* __restrict__ nrm,
                       const float* __restrict__ W1,
                       const float* __restrict__ b1,
                       const _Float16* __restrict__ w2h, // preconverted f16 tiles
                       float* __restrict__ out,
                       int ngroups)
{
    const int tid  = threadIdx.x;
    const int l    = tid & 63;
    const int r    = l & 15;         // A-row edge-in-group / D col o
    const int half = l >> 4;         // 0..3 -> k-range half*8..half*8+7

    // ---- persistent B fragments (17 tiles x 16B/lane; likely AGPR-resident) ----
    f16x8 bfrag[17];
    #pragma unroll
    for (int c = 0; c < 17; ++c) {
        bfrag[c] = *reinterpret_cast<const f16x8*>(
            w2h + ((c * 16 + r) * 32 + half * 8));
    }

    // ---- W1/b1 pinned to SGPRs ----
    float w1c0[16], w1c1[16], w1c2[16], b1s[16];
    #pragma unroll
    for (int c = 0; c < 16; ++c) {
        w1c0[c] = sgpr_f(W1 + c);
        w1c1[c] = sgpr_f(W1 + 16 + c);
        w1c2[c] = sgpr_f(W1 + 32 + c);
        b1s[c]  = sgpr_f(b1 + c);
    }

    const int wv = tid >> 6;
    int g = blockIdx.x * 4 + wv;        // nw=8192 <= ngroups: always has work
    const int nw = gridDim.x * 4;
    const int eisel = (half >= 2 ? N_EDGES : 0);

    // ---- pipeline state ----
    // xef_c : f16 fragment of CURRENT group's xe (converted at rotation)
    // xa/xb_p1 : raw float4 gather of NEXT group's xe
    // scalars: 2-level rotation (ev, nr, dst, idx)
    // deferred atomics: values + dsts of the PREVIOUS group, issued after
    //   the current iteration's loads (1 extra iteration of vmcnt slack).
    f16x8  xef_c;
    float  e0_c, e1_c, e2_c;
    float4 nr_c;
    int4   dst_c;
    int    idx_p1;
    float  e0_p1, e1_p1, e2_p1;
    float4 nr_p1;
    int4   dst_p1;
    float4 xa_p1, xb_p1;
    // deferred-atomic buffer (group g-nw); initialized empty via 0-norm trick
    float  dval[4] = {0.f, 0.f, 0.f, 0.f};
    int4   ddst = {0, 0, 0, 0};
    bool   have_deferred = false;

    {
        const int e0 = g * 16;
        const int idx0 = ei[eisel + e0 + r];
        const float* evp = ev + (size_t)(e0 + r) * 3;
        e0_c = evp[0]; e1_c = evp[1]; e2_c = evp[2];
        nr_c  = *reinterpret_cast<const float4*>(nrm + e0 + half * 4);
        dst_c = *reinterpret_cast<const int4*>(ei + N_EDGES + e0 + half * 4);
        const float4* xr = reinterpret_cast<const float4*>(
            x + (size_t)idx0 * 16 + (half & 1) * 8);
        const float4 xa = xr[0];
        const float4 xb = xr[1];
        xef_c[0] = (_Float16)xa.x; xef_c[1] = (_Float16)xa.y;
        xef_c[2] = (_Float16)xa.z; xef_c[3] = (_Float16)xa.w;
        xef_c[4] = (_Float16)xb.x; xef_c[5] = (_Float16)xb.y;
        xef_c[6] = (_Float16)xb.z; xef_c[7] = (_Float16)xb.w;
    }
    {
        const int gp1 = (g + nw < ngroups) ? g + nw : g;
        const int e0p = gp1 * 16;
        idx_p1 = ei[eisel + e0p + r];
        const float* evp = ev + (size_t)(e0p + r) * 3;
        e0_p1 = evp[0]; e1_p1 = evp[1]; e2_p1 = evp[2];
        nr_p1  = *reinterpret_cast<const float4*>(nrm + e0p + half * 4);
        dst_p1 = *reinterpret_cast<const int4*>(ei + N_EDGES + e0p + half * 4);
        const float4* xr1 = reinterpret_cast<const float4*>(
            x + (size_t)idx_p1 * 16 + (half & 1) * 8);
        xa_p1 = xr1[0];
        xb_p1 = xr1[1];
    }

    while (g < ngroups) {
        // ---- (1) scalar loads for g+2nw (idx/ev/nr/dst) ----
        const int gp2v = g + 2 * nw;
        const int gp2  = (gp2v < ngroups) ? gp2v : g;    // clamp: reload current
        const int e0p2 = gp2 * 16;
        const int idx_p2 = ei[eisel + e0p2 + r];
        const float* evp2 = ev + (size_t)(e0p2 + r) * 3;
        const float e0_p2 = evp2[0], e1_p2 = evp2[1], e2_p2 = evp2[2];
        const float4 nr_p2  = *reinterpret_cast<const float4*>(nrm + e0p2 + half * 4);
        const int4   dst_p2 = *reinterpret_cast<const int4*>(ei + N_EDGES + e0p2 + half * 4);

        // ---- (2) DEFERRED atomics for group g-nw (issued AFTER this
        //          iteration's loads: consuming those loads next iteration
        //          never forces these atomics to retire) ----
        if (have_deferred) {
            #pragma unroll
            for (int q = 0; q < 4; ++q) {
                const int* dd = reinterpret_cast<const int*>(&ddst);
                atomicAdd(out + (size_t)dd[q] * 16 + r, dval[q]);
            }
        }

        // ---- (3) bias tile (c=16): acc = xe @ b2^T ----
        f32x4 accA = __builtin_amdgcn_mfma_f32_16x16x32_f16(
            xef_c, bfrag[16], (f32x4){0.f, 0.f, 0.f, 0.f}, 0, 0, 0);
        f32x4 accB = (f32x4){0.f, 0.f, 0.f, 0.f};

        // ---- (4) 16 c-tiles: h inline, A = h*xe via packed f16 muls ----
        #pragma unroll
        for (int c = 0; c < 16; ++c) {
            float hc = fmaf(e2_c, w1c2[c],
                       fmaf(e1_c, w1c1[c],
                       fmaf(e0_c, w1c0[c], b1s[c])));
            hc = fmaxf(hc, 0.0f);
            const _Float16 hf = (_Float16)hc;
            f16x8 hv;
            #pragma unroll
            for (int j = 0; j < 8; ++j) hv[j] = hf;
            const f16x8 yf = xef_c * hv;        // 4x v_pk_mul_f16
            if (c & 1)
                accB = __builtin_amdgcn_mfma_f32_16x16x32_f16(yf, bfrag[c], accB, 0, 0, 0);
            else
                accA = __builtin_amdgcn_mfma_f32_16x16x32_f16(yf, bfrag[c], accA, 0, 0, 0);
        }

        // ---- (5) epilogue: tanh, norm scale -> DEFER the atomics ----
        // D layout (m89-verified, dtype-independent): col=l&15 (=o=r), row=half*4+q
        const float nrv[4] = {nr_c.x, nr_c.y, nr_c.z, nr_c.w};
        #pragma unroll
        for (int q = 0; q < 4; ++q) {
            const float sv = accA[q] + accB[q];
            const float t  = __expf(-2.0f * fabsf(sv));
            const float th = copysignf((1.0f - t) * __builtin_amdgcn_rcpf(1.0f + t), sv);
            dval[q] = th * nrv[q];
        }
        ddst = dst_c;
        have_deferred = true;

        // ---- (6) rotate pipeline state; convert next xe to f16 here ----
        xef_c[0] = (_Float16)xa_p1.x; xef_c[1] = (_Float16)xa_p1.y;
        xef_c[2] = (_Float16)xa_p1.z; xef_c[3] = (_Float16)xa_p1.w;
        xef_c[4] = (_Float16)xb_p1.x; xef_c[5] = (_Float16)xb_p1.y;
        xef_c[6] = (_Float16)xb_p1.z; xef_c[7] = (_Float16)xb_p1.w;
        e0_c = e0_p1; e1_c = e1_p1; e2_c = e2_p1;
        nr_c = nr_p1; dst_c = dst_p1;
        idx_p1 = idx_p2;
        e0_p1 = e0_p2; e1_p1 = e1_p2; e2_p1 = e2_p2;
        nr_p1 = nr_p2; dst_p1 = dst_p2;

        // ---- (7) x-gather for the (new) g+nw from resident idx ----
        {
            const float4* xr1 = reinterpret_cast<const float4*>(
                x + (size_t)idx_p1 * 16 + (half & 1) * 8);
            xa_p1 = xr1[0];
            xb_p1 = xr1[1];
        }

        g += nw;
    }

    // ---- drain the last deferred group ----
    #pragma unroll
    for (int q = 0; q < 4; ++q) {
        const int* dd = reinterpret_cast<const int*>(&ddst);
        atomicAdd(out + (size_t)dd[q] * 16 + r, dval[q]);
    }
}

extern "C" void kernel_launch(void* const* d_in, const int* in_sizes, int n_in,
                              void* d_out, int out_size, void* d_ws, size_t ws_size,
                              hipStream_t stream) {
    const float* x   = (const float*)d_in[0];
    const int*   ei  = (const int*)d_in[1];
    const float* ev  = (const float*)d_in[2];
    const float* nrm = (const float*)d_in[3];
    const float* W1  = (const float*)d_in[4];
    const float* b1  = (const float*)d_in[5];
    const float* W2  = (const float*)d_in[6];
    const float* b2  = (const float*)d_in[7];
    float* out = (float*)d_out;
    _Float16* w2h = (_Float16*)d_ws;     // 17*512*2 = 17408 B

    hipMemsetAsync(out, 0, (size_t)out_size * sizeof(float), stream);

    hipLaunchKernelGGL(w2_convert_kernel, dim3(34), dim3(256), 0, stream,
                       W2, b2, w2h);

    const int ngroups = N_EDGES / 16;   // 40000, exact
    hipLaunchKernelGGL(edge_hyper_kernel, dim3(2048), dim3(256), 0, stream,
                       x, ei, ev, nrm, W1, b1, w2h, out, ngroups);
}